// Round 2
// baseline (679.756 us; speedup 1.0000x reference)
//
#include <hip/hip_runtime.h>
#include <stdint.h>

typedef unsigned short ushort_t;
typedef __attribute__((ext_vector_type(8))) short bf16x8;
typedef __attribute__((ext_vector_type(4))) float f32x4;
typedef __attribute__((ext_vector_type(16))) float f32x16;
typedef __attribute__((ext_vector_type(4))) unsigned short us4;

static __device__ __forceinline__ unsigned short f2bf(float f) {
  union { float f; uint32_t u; } v; v.f = f;
  uint32_t u = v.u;
  u += 0x7FFFu + ((u >> 16) & 1u);
  return (unsigned short)(u >> 16);
}

static __device__ __forceinline__ float wredsum(float v) {
#pragma unroll
  for (int o = 32; o > 0; o >>= 1) v += __shfl_down(v, o, 64);
  return v;
}

// ---------------------------------------------------------------------------
// Weight fp32 -> bf16 conversion (Wq|Wk|Wv|Wp into one slab)
// ---------------------------------------------------------------------------
__global__ __launch_bounds__(256) void cvt_w(
    const float* __restrict__ Wq, const float* __restrict__ Wk,
    const float* __restrict__ Wv, const float* __restrict__ Wp,
    ushort_t* __restrict__ dst) {
  int m = blockIdx.y;
  const float* src = (m == 0) ? Wq : (m == 1) ? Wk : (m == 2) ? Wv : Wp;
  int i = blockIdx.x * 256 + threadIdx.x;  // float4 index, 16384 per matrix
  float4 v = ((const float4*)src)[i];
  us4 o;
  o.x = f2bf(v.x); o.y = f2bf(v.y); o.z = f2bf(v.z); o.w = f2bf(v.w);
  *(us4*)&dst[(size_t)m * 65536 + (size_t)i * 4] = o;
}

// ---------------------------------------------------------------------------
// GroupNorm stats: one block per (sel, b, g). mean + rstd over 8ch x 2304 px.
// ---------------------------------------------------------------------------
__global__ __launch_bounds__(256) void gn_stats(
    const float* __restrict__ x1, const float* __restrict__ x2,
    float* __restrict__ stats) {
  const int sel = blockIdx.x >> 8;
  const int bg = blockIdx.x & 255;  // b*32 + g
  const float* x = (sel ? x2 : x1) + (size_t)bg * 8 * 2304;
  float s = 0.f, ss = 0.f;
  for (int i = threadIdx.x; i < 4608; i += 256) {
    float4 v = ((const float4*)x)[i];
    s += v.x + v.y + v.z + v.w;
    ss += v.x * v.x + v.y * v.y + v.z * v.z + v.w * v.w;
  }
  s = wredsum(s);
  ss = wredsum(ss);
  __shared__ float ls[8];
  int wave = threadIdx.x >> 6, lane = threadIdx.x & 63;
  if (lane == 0) { ls[wave] = s; ls[4 + wave] = ss; }
  __syncthreads();
  if (threadIdx.x == 0) {
    float S = ls[0] + ls[1] + ls[2] + ls[3];
    float SS = ls[4] + ls[5] + ls[6] + ls[7];
    float mu = S * (1.f / 18432.f);
    float var = SS * (1.f / 18432.f) - mu * mu;
    stats[(sel * 256 + bg) * 2] = mu;
    stats[(sel * 256 + bg) * 2 + 1] = rsqrtf(var + 1e-6f);
  }
}

// ---------------------------------------------------------------------------
// GroupNorm apply + transpose: writes h_t[b][n][c] bf16. Block = (ntile,b,sel).
// ---------------------------------------------------------------------------
__global__ __launch_bounds__(256) void gn_apply(
    const float* __restrict__ x1, const float* __restrict__ x2,
    const float* __restrict__ gamma, const float* __restrict__ beta,
    const float* __restrict__ stats,
    ushort_t* __restrict__ h1t, ushort_t* __restrict__ h2t) {
  const int sel = blockIdx.z, b = blockIdx.y, nt = blockIdx.x;
  const int n0 = nt * 64;
  const float* x = (sel ? x2 : x1) + (size_t)b * 256 * 2304;
  ushort_t* ht = (sel ? h2t : h1t) + (size_t)b * 2304 * 256;
  const float* st = stats + (sel * 8 + b) * 64;  // 32 groups * 2
  __shared__ ushort_t lt[64 * 260];
#pragma unroll 4
  for (int it = 0; it < 64; ++it) {
    int flat = it * 256 + threadIdx.x;
    int c = flat >> 6, nn = flat & 63;
    float v = x[(size_t)c * 2304 + n0 + nn];
    int g = c >> 3;
    float mu = st[g * 2], rstd = st[g * 2 + 1];
    lt[nn * 260 + c] = f2bf((v - mu) * rstd * gamma[c] + beta[c]);
  }
  __syncthreads();
#pragma unroll 4
  for (int it = 0; it < 16; ++it) {
    int flat4 = it * 256 + threadIdx.x;
    int nn = flat4 >> 6, cq = flat4 & 63;
    us4 vv = *(const us4*)&lt[nn * 260 + cq * 4];
    *(us4*)&ht[(size_t)(n0 + nn) * 256 + cq * 4] = vv;
  }
}

// ---------------------------------------------------------------------------
// Generic both-K-contiguous MFMA GEMM.  C[m][n] = sum_k A[m][k]*B[n][k].
// 128x128 tile, BK=32, 256 threads (4 waves, 2x2 of 64x64), 16x16x32 bf16.
// MODE_OUT: 0 bf16 +bias[col] | 1 bf16 +bias[row]
//           5 fp32 = acc + bias[row] + res[row][col]
// ---------------------------------------------------------------------------
template <int MODE_OUT>
__global__ __launch_bounds__(256) void gemm_bt(
    const ushort_t* __restrict__ Av, const ushort_t* __restrict__ Bv,
    void* __restrict__ Cv, int M, int N, int K, long sA, long sB, long sC,
    const float* __restrict__ bias, const float* __restrict__ res, long sRes) {
  __shared__ ushort_t lA[128 * 32];
  __shared__ ushort_t lB[128 * 32];
  const int tid = threadIdx.x;
  const int lane = tid & 63, wave = tid >> 6;
  const int wm = wave >> 1, wn = wave & 1;
  const int bz = blockIdx.z;
  const int bM = blockIdx.x * 128, bN = blockIdx.y * 128;

  const ushort_t* B = Bv + (size_t)bz * sB + (size_t)bN * K;
  const ushort_t* Ab = Av + (size_t)bz * sA + (size_t)bM * K;

  f32x4 acc[4][4];
#pragma unroll
  for (int m = 0; m < 4; ++m)
#pragma unroll
    for (int n = 0; n < 4; ++n) acc[m][n] = (f32x4){0.f, 0.f, 0.f, 0.f};

  const int nK = K >> 5;
  for (int kt = 0; kt < nK; ++kt) {
    __syncthreads();
#pragma unroll
    for (int i = 0; i < 2; ++i) {
      int c = i * 256 + tid;
      int row = c >> 2, cb = (c & 3) * 8;
      const ushort_t* src = B + (size_t)row * K + kt * 32 + cb;
      __builtin_amdgcn_global_load_lds(
          (const __attribute__((address_space(1))) uint32_t*)src,
          (__attribute__((address_space(3))) uint32_t*)((char*)lB + i * 4096 +
                                                        wave * 1024),
          16, 0, 0);
    }
#pragma unroll
    for (int i = 0; i < 2; ++i) {
      int c = i * 256 + tid;
      int row = c >> 2, cb = (c & 3) * 8;
      const ushort_t* src = Ab + (size_t)row * K + kt * 32 + cb;
      __builtin_amdgcn_global_load_lds(
          (const __attribute__((address_space(1))) uint32_t*)src,
          (__attribute__((address_space(3))) uint32_t*)((char*)lA + i * 4096 +
                                                        wave * 1024),
          16, 0, 0);
    }
    __syncthreads();

    bf16x8 af[4], bfr[4];
    const int ko = (lane >> 4) * 8;
    const int rb = lane & 15;
#pragma unroll
    for (int m = 0; m < 4; ++m)
      af[m] = *(const bf16x8*)&lA[(wm * 64 + m * 16 + rb) * 32 + ko];
#pragma unroll
    for (int n = 0; n < 4; ++n)
      bfr[n] = *(const bf16x8*)&lB[(wn * 64 + n * 16 + rb) * 32 + ko];
#pragma unroll
    for (int m = 0; m < 4; ++m)
#pragma unroll
      for (int n = 0; n < 4; ++n)
        acc[m][n] =
            __builtin_amdgcn_mfma_f32_16x16x32_bf16(af[m], bfr[n], acc[m][n],
                                                    0, 0, 0);
  }

  const int r0 = (lane >> 4) * 4;
  const int c0 = lane & 15;
#pragma unroll
  for (int m = 0; m < 4; ++m) {
#pragma unroll
    for (int n = 0; n < 4; ++n) {
#pragma unroll
      for (int j = 0; j < 4; ++j) {
        int row = bM + wm * 64 + m * 16 + r0 + j;
        int col = bN + wn * 64 + n * 16 + c0;
        float v = acc[m][n][j];
        size_t idx = (size_t)row * N + col;
        if (MODE_OUT == 0) {
          ((ushort_t*)Cv + (size_t)bz * sC)[idx] = f2bf(v + bias[col]);
        } else if (MODE_OUT == 1) {
          ((ushort_t*)Cv + (size_t)bz * sC)[idx] = f2bf(v + bias[row]);
        } else {
          ((float*)Cv + (size_t)bz * sC)[idx] =
              v + bias[row] + (res + (size_t)bz * sRes)[idx];
        }
      }
    }
  }
}

// ---------------------------------------------------------------------------
// Fused dual attention (flash-style, fixed-shift softmax):
//   att1 = softmax(s*q1k1) @ v^T ; att2 = softmax(s*(q1k1+q2k2)) @ v^T
// Block: 64 q-rows, 4 waves (wi = i-half, ws = j-half for scores / c-half
// for PV). Q in registers; K/V straight from L2 (batch pinned to XCD via
// bid&7). P exchanged via swizzled double-buffered LDS. 32x32x16 bf16 MFMA.
// ---------------------------------------------------------------------------
__global__ __launch_bounds__(256, 1) void flash_attn(
    const ushort_t* __restrict__ q1t, const ushort_t* __restrict__ k1t,
    const ushort_t* __restrict__ q2t, const ushort_t* __restrict__ k2t,
    const ushort_t* __restrict__ vB, ushort_t* __restrict__ att1,
    ushort_t* __restrict__ att2) {
  const int bid = blockIdx.x;
  const int b = bid & 7;    // batch -> XCD affinity
  const int qb = bid >> 3;  // 0..35
  const int tid = threadIdx.x;
  const int lane = tid & 63;
  const int w = tid >> 6;
  const int wi = w >> 1;  // i-half
  const int ws = w & 1;   // j-half (scores) / c-half (PV)
  const int l31 = lane & 31;
  const int h = lane >> 5;

  const size_t sH = (size_t)2304 * 256;
  const ushort_t* q1 = q1t + b * sH;
  const ushort_t* q2 = q2t + b * sH;
  const ushort_t* k1 = k1t + b * sH;
  const ushort_t* k2 = k2t + b * sH;
  const ushort_t* v = vB + b * sH;  // [c][n], n-stride 1, c-stride 2304

  __shared__ char pmem[2][2][8192];  // [buf][set][64i x 64j bf16, swizzled]
  __shared__ float l_lds[2][64];

  // ---- Q fragments (held in registers for whole kernel) ----
  bf16x8 qf1[16], qf2[16];
  const int qrow = qb * 64 + wi * 32 + l31;
  {
    const ushort_t* q1p = q1 + (size_t)qrow * 256 + h * 8;
    const ushort_t* q2p = q2 + (size_t)qrow * 256 + h * 8;
#pragma unroll
    for (int ck = 0; ck < 16; ++ck) {
      qf1[ck] = *(const bf16x8*)(q1p + ck * 16);
      qf2[ck] = *(const bf16x8*)(q2p + ck * 16);
    }
  }

  f32x16 o1[4], o2[4];
#pragma unroll
  for (int cb = 0; cb < 4; ++cb)
#pragma unroll
    for (int r = 0; r < 16; ++r) { o1[cb][r] = 0.f; o2[cb][r] = 0.f; }
  float lp1 = 0.f, lp2 = 0.f;

  const int i_loc = wi * 32 + l31;
  const int iswz = (i_loc & 7) << 4;

  for (int t = 0; t < 36; ++t) {
    // ---- scores: S^T = mfma(K, Q); wave computes [32j x 32i] quadrant ----
    f32x16 s1, s2;
#pragma unroll
    for (int r = 0; r < 16; ++r) { s1[r] = 0.f; s2[r] = 0.f; }
    const ushort_t* k1p = k1 + (size_t)(t * 64 + ws * 32 + l31) * 256 + h * 8;
    const ushort_t* k2p = k2 + (size_t)(t * 64 + ws * 32 + l31) * 256 + h * 8;
#pragma unroll
    for (int ck = 0; ck < 16; ++ck) {
      bf16x8 kf1 = *(const bf16x8*)(k1p + ck * 16);
      s1 = __builtin_amdgcn_mfma_f32_32x32x16_bf16(kf1, qf1[ck], s1, 0, 0, 0);
      bf16x8 kf2 = *(const bf16x8*)(k2p + ck * 16);
      s2 = __builtin_amdgcn_mfma_f32_32x32x16_bf16(kf2, qf2[ck], s2, 0, 0, 0);
    }
    // ---- P = exp(w - 8)  (fixed shift; |w| <~ 8 so no overflow) ----
    const int buf = t & 1;
    float e1[16], e12[16];
#pragma unroll
    for (int r = 0; r < 16; ++r) {
      e1[r] = __expf(s1[r] * 0.0625f - 8.f);
      e12[r] = __expf((s1[r] + s2[r]) * 0.0625f - 8.f);
      lp1 += e1[r];
      lp2 += e12[r];
    }
    // write P tiles to LDS: C/D reg r -> j = ws*32 + (r&3) + 8*(r>>2) + 4h
#pragma unroll
    for (int g = 0; g < 4; ++g) {
      int jb = ws * 32 + g * 8 + h * 4;
      int off = (i_loc * 128 + jb * 2) ^ iswz;
      uint32_t u0 =
          (uint32_t)f2bf(e1[4 * g]) | ((uint32_t)f2bf(e1[4 * g + 1]) << 16);
      uint32_t u1 = (uint32_t)f2bf(e1[4 * g + 2]) |
                    ((uint32_t)f2bf(e1[4 * g + 3]) << 16);
      *(uint2*)(&pmem[buf][0][off]) = make_uint2(u0, u1);
      uint32_t w0 =
          (uint32_t)f2bf(e12[4 * g]) | ((uint32_t)f2bf(e12[4 * g + 1]) << 16);
      uint32_t w1 = (uint32_t)f2bf(e12[4 * g + 2]) |
                    ((uint32_t)f2bf(e12[4 * g + 3]) << 16);
      *(uint2*)(&pmem[buf][1][off]) = make_uint2(w0, w1);
    }
    __syncthreads();
    // ---- PV: O += P @ V^T; wave computes [32i x 128c] ----
#pragma unroll
    for (int jc = 0; jc < 4; ++jc) {
      int aoff = (i_loc * 128 + jc * 32 + h * 16) ^ iswz;
      bf16x8 pa1 = *(const bf16x8*)(&pmem[buf][0][aoff]);
      bf16x8 pa2 = *(const bf16x8*)(&pmem[buf][1][aoff]);
      const ushort_t* vp =
          v + (size_t)(ws * 128 + l31) * 2304 + t * 64 + jc * 16 + h * 8;
#pragma unroll
      for (int cb = 0; cb < 4; ++cb) {
        bf16x8 vf = *(const bf16x8*)(vp + (size_t)cb * 32 * 2304);
        o1[cb] =
            __builtin_amdgcn_mfma_f32_32x32x16_bf16(pa1, vf, o1[cb], 0, 0, 0);
        o2[cb] =
            __builtin_amdgcn_mfma_f32_32x32x16_bf16(pa2, vf, o2[cb], 0, 0, 0);
      }
    }
  }

  // ---- reduce softmax denominators across (h, ws) ----
  lp1 += __shfl_xor(lp1, 32, 64);
  lp2 += __shfl_xor(lp2, 32, 64);
  __syncthreads();
  if (ws == 0 && lane < 32) {
    l_lds[0][i_loc] = lp1;
    l_lds[1][i_loc] = lp2;
  }
  __syncthreads();
  if (ws == 1 && lane < 32) {
    l_lds[0][i_loc] += lp1;
    l_lds[1][i_loc] += lp2;
  }
  __syncthreads();

  // ---- epilogue: O / l -> attT [n][c] bf16 ----
  ushort_t* a1p = att1 + ((size_t)b * 2304 + qb * 64) * 256;
  ushort_t* a2p = att2 + ((size_t)b * 2304 + qb * 64) * 256;
#pragma unroll
  for (int r = 0; r < 16; ++r) {
    int irow = wi * 32 + (r & 3) + 8 * (r >> 2) + 4 * h;
    float rl1 = 1.f / l_lds[0][irow];
    float rl2 = 1.f / l_lds[1][irow];
#pragma unroll
    for (int cb = 0; cb < 4; ++cb) {
      int col = ws * 128 + cb * 32 + l31;
      a1p[(size_t)irow * 256 + col] = f2bf(o1[cb][r] * rl1);
      a2p[(size_t)irow * 256 + col] = f2bf(o2[cb][r] * rl2);
    }
  }
}

// ---------------------------------------------------------------------------
extern "C" void kernel_launch(void* const* d_in, const int* in_sizes, int n_in,
                              void* d_out, int out_size, void* d_ws,
                              size_t ws_size, hipStream_t stream) {
  (void)in_sizes; (void)n_in; (void)out_size; (void)ws_size;
  const float* x1 = (const float*)d_in[0];
  const float* x2 = (const float*)d_in[1];
  const float* gamma = (const float*)d_in[2];
  const float* beta = (const float*)d_in[3];
  const float* Wq = (const float*)d_in[4];
  const float* bq = (const float*)d_in[5];
  const float* Wk = (const float*)d_in[6];
  const float* bk = (const float*)d_in[7];
  const float* Wv = (const float*)d_in[8];
  const float* bv = (const float*)d_in[9];
  const float* Wp = (const float*)d_in[10];
  const float* bp = (const float*)d_in[11];
  float* out = (float*)d_out;

  const int C = 256, N = 2304;
  const long sH = (long)N * C;
  const long sX = (long)C * N;
  const size_t HE = (size_t)8 * N * C;

  char* ws = (char*)d_ws;
  ushort_t* Wbf = (ushort_t*)ws;         // 4 * 65536 bf16
  float* stats = (float*)(ws + 524288);  // 2*8*32*2 fp32
  ushort_t* h1t = (ushort_t*)(ws + 528384);
  ushort_t* h2t = h1t + HE;
  ushort_t* q1t = h2t + HE;
  ushort_t* k1t = q1t + HE;
  ushort_t* q2t = k1t + HE;
  ushort_t* k2t = q2t + HE;
  ushort_t* vB = k2t + HE;    // [b][c][n]
  ushort_t* att1 = vB + HE;   // [b][n][c]
  ushort_t* att2 = att1 + HE;

  cvt_w<<<dim3(64, 4), 256, 0, stream>>>(Wq, Wk, Wv, Wp, Wbf);
  gn_stats<<<512, 256, 0, stream>>>(x1, x2, stats);
  gn_apply<<<dim3(36, 8, 2), 256, 0, stream>>>(x1, x2, gamma, beta, stats, h1t,
                                               h2t);

  gemm_bt<0><<<dim3(18, 2, 8), 256, 0, stream>>>(h1t, Wbf + 0 * 65536, q1t, N,
                                                 C, C, sH, 0, sH, bq, nullptr,
                                                 0);
  gemm_bt<0><<<dim3(18, 2, 8), 256, 0, stream>>>(h1t, Wbf + 1 * 65536, k1t, N,
                                                 C, C, sH, 0, sH, bk, nullptr,
                                                 0);
  gemm_bt<0><<<dim3(18, 2, 8), 256, 0, stream>>>(h2t, Wbf + 0 * 65536, q2t, N,
                                                 C, C, sH, 0, sH, bq, nullptr,
                                                 0);
  gemm_bt<0><<<dim3(18, 2, 8), 256, 0, stream>>>(h2t, Wbf + 1 * 65536, k2t, N,
                                                 C, C, sH, 0, sH, bk, nullptr,
                                                 0);
  gemm_bt<1><<<dim3(2, 18, 8), 256, 0, stream>>>(Wbf + 2 * 65536, h1t, vB, C,
                                                 N, C, 0, sH, sX, bv, nullptr,
                                                 0);

  flash_attn<<<288, 256, 0, stream>>>(q1t, k1t, q2t, k2t, vB, att1, att2);

  const size_t half = (size_t)8 * C * N;
  gemm_bt<5><<<dim3(2, 18, 8), 256, 0, stream>>>(Wbf + 3 * 65536, att1, out, C,
                                                 N, C, 0, sH, sX, bp, x1, sX);
  gemm_bt<5><<<dim3(2, 18, 8), 256, 0, stream>>>(Wbf + 3 * 65536, att2,
                                                 out + half, C, N, C, 0, sH,
                                                 sX, bp, x1, sX);
}

// Round 4
// 671.286 us; speedup vs baseline: 1.0126x; 1.0126x over previous
//
#include <hip/hip_runtime.h>
#include <stdint.h>

typedef unsigned short ushort_t;
typedef __attribute__((ext_vector_type(8))) short bf16x8;
typedef __attribute__((ext_vector_type(4))) float f32x4;
typedef __attribute__((ext_vector_type(16))) float f32x16;
typedef __attribute__((ext_vector_type(4))) unsigned short us4;

static __device__ __forceinline__ unsigned short f2bf(float f) {
  union { float f; uint32_t u; } v; v.f = f;
  uint32_t u = v.u;
  u += 0x7FFFu + ((u >> 16) & 1u);
  return (unsigned short)(u >> 16);
}

static __device__ __forceinline__ float wredsum(float v) {
#pragma unroll
  for (int o = 32; o > 0; o >>= 1) v += __shfl_down(v, o, 64);
  return v;
}

// ---------------------------------------------------------------------------
// Weight fp32 -> bf16 conversion (Wq|Wk|Wv|Wp into one slab)
// ---------------------------------------------------------------------------
__global__ __launch_bounds__(256) void cvt_w(
    const float* __restrict__ Wq, const float* __restrict__ Wk,
    const float* __restrict__ Wv, const float* __restrict__ Wp,
    ushort_t* __restrict__ dst) {
  int m = blockIdx.y;
  const float* src = (m == 0) ? Wq : (m == 1) ? Wk : (m == 2) ? Wv : Wp;
  int i = blockIdx.x * 256 + threadIdx.x;  // float4 index, 16384 per matrix
  float4 v = ((const float4*)src)[i];
  us4 o;
  o.x = f2bf(v.x); o.y = f2bf(v.y); o.z = f2bf(v.z); o.w = f2bf(v.w);
  *(us4*)&dst[(size_t)m * 65536 + (size_t)i * 4] = o;
}

__global__ __launch_bounds__(512) void pack_bqk(const float* __restrict__ bq,
                                                const float* __restrict__ bk,
                                                float* __restrict__ bqk) {
  int i = threadIdx.x;
  bqk[i] = (i < 256) ? bq[i] : bk[i - 256];
}

// ---------------------------------------------------------------------------
// GroupNorm stats: one block per (sel, b, g). mean + rstd over 8ch x 2304 px.
// ---------------------------------------------------------------------------
__global__ __launch_bounds__(256) void gn_stats(
    const float* __restrict__ x1, const float* __restrict__ x2,
    float* __restrict__ stats) {
  const int sel = blockIdx.x >> 8;
  const int bg = blockIdx.x & 255;  // b*32 + g
  const float* x = (sel ? x2 : x1) + (size_t)bg * 8 * 2304;
  float s = 0.f, ss = 0.f;
  for (int i = threadIdx.x; i < 4608; i += 256) {
    float4 v = ((const float4*)x)[i];
    s += v.x + v.y + v.z + v.w;
    ss += v.x * v.x + v.y * v.y + v.z * v.z + v.w * v.w;
  }
  s = wredsum(s);
  ss = wredsum(ss);
  __shared__ float ls[8];
  int wave = threadIdx.x >> 6, lane = threadIdx.x & 63;
  if (lane == 0) { ls[wave] = s; ls[4 + wave] = ss; }
  __syncthreads();
  if (threadIdx.x == 0) {
    float S = ls[0] + ls[1] + ls[2] + ls[3];
    float SS = ls[4] + ls[5] + ls[6] + ls[7];
    float mu = S * (1.f / 18432.f);
    float var = SS * (1.f / 18432.f) - mu * mu;
    stats[(sel * 256 + bg) * 2] = mu;
    stats[(sel * 256 + bg) * 2 + 1] = rsqrtf(var + 1e-6f);
  }
}

// ---------------------------------------------------------------------------
// GroupNorm apply + transpose: writes h_t[b][n][c] bf16. Block = (ntile,b,sel).
// ---------------------------------------------------------------------------
__global__ __launch_bounds__(256) void gn_apply(
    const float* __restrict__ x1, const float* __restrict__ x2,
    const float* __restrict__ gamma, const float* __restrict__ beta,
    const float* __restrict__ stats,
    ushort_t* __restrict__ h1t, ushort_t* __restrict__ h2t) {
  const int sel = blockIdx.z, b = blockIdx.y, nt = blockIdx.x;
  const int n0 = nt * 64;
  const float* x = (sel ? x2 : x1) + (size_t)b * 256 * 2304;
  ushort_t* ht = (sel ? h2t : h1t) + (size_t)b * 2304 * 256;
  const float* st = stats + (sel * 8 + b) * 64;  // 32 groups * 2
  __shared__ ushort_t lt[64 * 260];
#pragma unroll 4
  for (int it = 0; it < 64; ++it) {
    int flat = it * 256 + threadIdx.x;
    int c = flat >> 6, nn = flat & 63;
    float v = x[(size_t)c * 2304 + n0 + nn];
    int g = c >> 3;
    float mu = st[g * 2], rstd = st[g * 2 + 1];
    lt[nn * 260 + c] = f2bf((v - mu) * rstd * gamma[c] + beta[c]);
  }
  __syncthreads();
#pragma unroll 4
  for (int it = 0; it < 16; ++it) {
    int flat4 = it * 256 + threadIdx.x;
    int nn = flat4 >> 6, cq = flat4 & 63;
    us4 vv = *(const us4*)&lt[nn * 260 + cq * 4];
    *(us4*)&ht[(size_t)(n0 + nn) * 256 + cq * 4] = vv;
  }
}

// ---------------------------------------------------------------------------
// Generic both-K-contiguous MFMA GEMM.  C[m][n] = sum_k A[m][k]*B[n][k].
// 128x128 tile, BK=32, 256 threads (4 waves, 2x2 of 64x64), 16x16x32 bf16.
// MODE_OUT: 0 bf16 +bias[col] | 1 bf16 +bias[row]
//           5 fp32 = acc + bias[row] + res[row][col]
// ---------------------------------------------------------------------------
template <int MODE_OUT>
__global__ __launch_bounds__(256) void gemm_bt(
    const ushort_t* __restrict__ Av, const ushort_t* __restrict__ Bv,
    void* __restrict__ Cv, int M, int N, int K, long sA, long sB, long sC,
    const float* __restrict__ bias, const float* __restrict__ res, long sRes) {
  __shared__ ushort_t lA[128 * 32];
  __shared__ ushort_t lB[128 * 32];
  const int tid = threadIdx.x;
  const int lane = tid & 63, wave = tid >> 6;
  const int wm = wave >> 1, wn = wave & 1;
  const int bz = blockIdx.z;
  const int bM = blockIdx.x * 128, bN = blockIdx.y * 128;

  const ushort_t* B = Bv + (size_t)bz * sB + (size_t)bN * K;
  const ushort_t* Ab = Av + (size_t)bz * sA + (size_t)bM * K;

  f32x4 acc[4][4];
#pragma unroll
  for (int m = 0; m < 4; ++m)
#pragma unroll
    for (int n = 0; n < 4; ++n) acc[m][n] = (f32x4){0.f, 0.f, 0.f, 0.f};

  const int nK = K >> 5;
  for (int kt = 0; kt < nK; ++kt) {
    __syncthreads();
#pragma unroll
    for (int i = 0; i < 2; ++i) {
      int c = i * 256 + tid;
      int row = c >> 2, cb = (c & 3) * 8;
      const ushort_t* src = B + (size_t)row * K + kt * 32 + cb;
      __builtin_amdgcn_global_load_lds(
          (const __attribute__((address_space(1))) uint32_t*)src,
          (__attribute__((address_space(3))) uint32_t*)((char*)lB + i * 4096 +
                                                        wave * 1024),
          16, 0, 0);
    }
#pragma unroll
    for (int i = 0; i < 2; ++i) {
      int c = i * 256 + tid;
      int row = c >> 2, cb = (c & 3) * 8;
      const ushort_t* src = Ab + (size_t)row * K + kt * 32 + cb;
      __builtin_amdgcn_global_load_lds(
          (const __attribute__((address_space(1))) uint32_t*)src,
          (__attribute__((address_space(3))) uint32_t*)((char*)lA + i * 4096 +
                                                        wave * 1024),
          16, 0, 0);
    }
    __syncthreads();

    bf16x8 af[4], bfr[4];
    const int ko = (lane >> 4) * 8;
    const int rb = lane & 15;
#pragma unroll
    for (int m = 0; m < 4; ++m)
      af[m] = *(const bf16x8*)&lA[(wm * 64 + m * 16 + rb) * 32 + ko];
#pragma unroll
    for (int n = 0; n < 4; ++n)
      bfr[n] = *(const bf16x8*)&lB[(wn * 64 + n * 16 + rb) * 32 + ko];
#pragma unroll
    for (int m = 0; m < 4; ++m)
#pragma unroll
      for (int n = 0; n < 4; ++n)
        acc[m][n] =
            __builtin_amdgcn_mfma_f32_16x16x32_bf16(af[m], bfr[n], acc[m][n],
                                                    0, 0, 0);
  }

  const int r0 = (lane >> 4) * 4;
  const int c0 = lane & 15;
#pragma unroll
  for (int m = 0; m < 4; ++m) {
#pragma unroll
    for (int n = 0; n < 4; ++n) {
#pragma unroll
      for (int j = 0; j < 4; ++j) {
        int row = bM + wm * 64 + m * 16 + r0 + j;
        int col = bN + wn * 64 + n * 16 + c0;
        float v = acc[m][n][j];
        size_t idx = (size_t)row * N + col;
        if (MODE_OUT == 0) {
          ((ushort_t*)Cv + (size_t)bz * sC)[idx] = f2bf(v + bias[col]);
        } else if (MODE_OUT == 1) {
          ((ushort_t*)Cv + (size_t)bz * sC)[idx] = f2bf(v + bias[row]);
        } else {
          ((float*)Cv + (size_t)bz * sC)[idx] =
              v + bias[row] + (res + (size_t)bz * sRes)[idx];
        }
      }
    }
  }
}

// ---------------------------------------------------------------------------
// Fused dual attention, pair-split + software-pipelined:
//   waves 0/1: att1 = softmax(s*q1k1) @ v^T      (j/c halves)
//   waves 2/3: att2 = softmax(s*(q1k1+q2k2)) @ v^T
// Q tile = 32 rows. Raw s1 passed via swizzled f32 LDS; P tiles via swizzled
// bf16 LDS. Fixed-shift softmax exp(w-8), denominator accumulated in regs.
// Phase 1 of tile t: scores(t) + PV(t-1) (32 MFMA / wave, all waves).
// Phase 2: cross pair reads s1, writes P12. Two barriers per tile.
// ---------------------------------------------------------------------------
__global__ __launch_bounds__(256, 2) void flash_attn(
    const ushort_t* __restrict__ qk1, const ushort_t* __restrict__ qk2,
    const ushort_t* __restrict__ vB, ushort_t* __restrict__ att1,
    ushort_t* __restrict__ att2) {
  const int bid = blockIdx.x;
  const int b = bid & 7;    // batch -> XCD affinity
  const int qb = bid >> 3;  // 0..71, 32 q-rows each
  const int tid = threadIdx.x;
  const int lane = tid & 63;
  const int w = tid >> 6;
  const int grp = w >> 1;  // 0 = self pair, 1 = cross pair
  const int wp = w & 1;    // j-half (scores) / c-half (PV)
  const int l31 = lane & 31;
  const int h = lane >> 5;

  const size_t sQK = (size_t)2304 * 512;
  const size_t sV = (size_t)2304 * 256;
  const ushort_t* qk = (grp ? qk2 : qk1) + b * sQK;  // [n][512]: q | k
  const ushort_t* kk = qk + 256;
  const ushort_t* v = vB + b * sV;  // [c][n]

  __shared__ ushort_t P1[2][32 * 64];  // self probs, double-buffered, swizzled
  __shared__ ushort_t P12[32 * 64];    // cross probs, swizzled
  __shared__ float S1[32 * 64];        // raw self scores, swizzled
  __shared__ float red[2][32];

  // ---- Q fragments (persist in registers) ----
  bf16x8 qf[16];
  {
    const ushort_t* qp = qk + (size_t)(qb * 32 + l31) * 512 + h * 8;
#pragma unroll
    for (int ck = 0; ck < 16; ++ck) qf[ck] = *(const bf16x8*)(qp + ck * 16);
  }

  f32x16 o[4];
#pragma unroll
  for (int cb = 0; cb < 4; ++cb)
#pragma unroll
    for (int r = 0; r < 16; ++r) o[cb][r] = 0.f;
  float lp = 0.f;
  const int iswz = (l31 & 7) << 4;

  auto do_pv = [&](int tt) {
    const ushort_t* pb = grp ? P12 : P1[tt & 1];
    const ushort_t* vt = v + (size_t)tt * 64;
#pragma unroll
    for (int jc = 0; jc < 4; ++jc) {
      bf16x8 pa = *(const bf16x8*)((const char*)pb +
                                   ((l31 * 128 + jc * 32 + h * 16) ^ iswz));
#pragma unroll
      for (int cb = 0; cb < 4; ++cb) {
        bf16x8 vf = *(const bf16x8*)(vt +
                                     (size_t)(wp * 128 + cb * 32 + l31) * 2304 +
                                     jc * 16 + h * 8);
        o[cb] =
            __builtin_amdgcn_mfma_f32_32x32x16_bf16(pa, vf, o[cb], 0, 0, 0);
      }
    }
  };

  f32x16 s2save;
  for (int t = 0; t < 36; ++t) {
    // ---------------- phase 1: scores(t) + PV(t-1) ----------------
    f32x16 s;
#pragma unroll
    for (int r = 0; r < 16; ++r) s[r] = 0.f;
    {
      const ushort_t* kp =
          kk + (size_t)(t * 64 + wp * 32 + l31) * 512 + h * 8;
#pragma unroll
      for (int ck = 0; ck < 16; ++ck) {
        bf16x8 kf = *(const bf16x8*)(kp + ck * 16);
        s = __builtin_amdgcn_mfma_f32_32x32x16_bf16(kf, qf[ck], s, 0, 0, 0);
      }
    }
    if (t > 0) do_pv(t - 1);
    if (grp == 0) {
      float e[16];
#pragma unroll
      for (int r = 0; r < 16; ++r) {
        e[r] = __expf(s[r] * 0.0625f - 8.f);
        lp += e[r];
      }
      char* p1 = (char*)P1[t & 1];
      char* s1 = (char*)S1;
#pragma unroll
      for (int g = 0; g < 4; ++g) {
        uint32_t u0 = (uint32_t)f2bf(e[4 * g]) |
                      ((uint32_t)f2bf(e[4 * g + 1]) << 16);
        uint32_t u1 = (uint32_t)f2bf(e[4 * g + 2]) |
                      ((uint32_t)f2bf(e[4 * g + 3]) << 16);
        *(uint2*)(p1 + ((l31 * 128 + wp * 64 + g * 16 + h * 8) ^ iswz)) =
            make_uint2(u0, u1);
        float4 sv = make_float4(s[4 * g], s[4 * g + 1], s[4 * g + 2],
                                s[4 * g + 3]);
        *(float4*)(s1 + ((l31 * 256 + wp * 128 + g * 32 + h * 16) ^ iswz)) =
            sv;
      }
    } else {
      s2save = s;
    }
    __syncthreads();
    // ---------------- phase 2: cross pair builds P12(t) ----------------
    if (grp == 1) {
      const char* s1 = (const char*)S1;
      char* p12 = (char*)P12;
#pragma unroll
      for (int g = 0; g < 4; ++g) {
        float4 sv = *(const float4*)(s1 + ((l31 * 256 + wp * 128 + g * 32 +
                                            h * 16) ^ iswz));
        float e0 = __expf((sv.x + s2save[4 * g + 0]) * 0.0625f - 8.f);
        float e1 = __expf((sv.y + s2save[4 * g + 1]) * 0.0625f - 8.f);
        float e2 = __expf((sv.z + s2save[4 * g + 2]) * 0.0625f - 8.f);
        float e3 = __expf((sv.w + s2save[4 * g + 3]) * 0.0625f - 8.f);
        lp += e0 + e1 + e2 + e3;
        uint32_t u0 = (uint32_t)f2bf(e0) | ((uint32_t)f2bf(e1) << 16);
        uint32_t u1 = (uint32_t)f2bf(e2) | ((uint32_t)f2bf(e3) << 16);
        *(uint2*)(p12 + ((l31 * 128 + wp * 64 + g * 16 + h * 8) ^ iswz)) =
            make_uint2(u0, u1);
      }
    }
    __syncthreads();
  }
  do_pv(35);

  // ---- denominators: combine h halves, then the two waves of each pair ----
  lp += __shfl_xor(lp, 32, 64);
  __syncthreads();
  if (wp == 0 && lane < 32) red[grp][l31] = lp;
  __syncthreads();
  if (wp == 1 && lane < 32) red[grp][l31] += lp;
  __syncthreads();

  ushort_t* ap = (grp ? att2 : att1) + ((size_t)b * 2304 + qb * 32) * 256;
#pragma unroll
  for (int r = 0; r < 16; ++r) {
    int irow = (r & 3) + 8 * (r >> 2) + 4 * h;
    float rl = 1.f / red[grp][irow];
#pragma unroll
    for (int cb = 0; cb < 4; ++cb) {
      int col = wp * 128 + cb * 32 + l31;
      ap[(size_t)irow * 256 + col] = f2bf(o[cb][r] * rl);
    }
  }
}

// ---------------------------------------------------------------------------
extern "C" void kernel_launch(void* const* d_in, const int* in_sizes, int n_in,
                              void* d_out, int out_size, void* d_ws,
                              size_t ws_size, hipStream_t stream) {
  (void)in_sizes; (void)n_in; (void)out_size; (void)ws_size;
  const float* x1 = (const float*)d_in[0];
  const float* x2 = (const float*)d_in[1];
  const float* gamma = (const float*)d_in[2];
  const float* beta = (const float*)d_in[3];
  const float* Wq = (const float*)d_in[4];
  const float* bq = (const float*)d_in[5];
  const float* Wk = (const float*)d_in[6];
  const float* bk = (const float*)d_in[7];
  const float* Wv = (const float*)d_in[8];
  const float* bv = (const float*)d_in[9];
  const float* Wp = (const float*)d_in[10];
  const float* bp = (const float*)d_in[11];
  float* out = (float*)d_out;

  const int C = 256, N = 2304;
  const long sH = (long)N * C;
  const long sQK = (long)N * 512;
  const long sX = (long)C * N;
  const size_t HE = (size_t)8 * N * C;

  char* ws = (char*)d_ws;
  ushort_t* Wbf = (ushort_t*)ws;         // 4 * 65536 bf16
  float* stats = (float*)(ws + 524288);  // 1024 fp32
  float* bqk = (float*)(ws + 528384);    // 512 fp32
  ushort_t* h1t = (ushort_t*)(ws + 532480);
  ushort_t* h2t = h1t + HE;
  ushort_t* qk1 = h2t + HE;        // [b][n][512]
  ushort_t* qk2 = qk1 + 2 * HE;
  ushort_t* vB = qk2 + 2 * HE;     // [b][c][n]
  ushort_t* att1 = vB + HE;        // [b][n][c]
  ushort_t* att2 = att1 + HE;

  cvt_w<<<dim3(64, 4), 256, 0, stream>>>(Wq, Wk, Wv, Wp, Wbf);
  pack_bqk<<<1, 512, 0, stream>>>(bq, bk, bqk);
  gn_stats<<<512, 256, 0, stream>>>(x1, x2, stats);
  gn_apply<<<dim3(36, 8, 2), 256, 0, stream>>>(x1, x2, gamma, beta, stats, h1t,
                                               h2t);

  // fused q|k projections (N=512), v projection
  gemm_bt<0><<<dim3(18, 4, 8), 256, 0, stream>>>(h1t, Wbf, qk1, N, 512, C, sH,
                                                 0, sQK, bqk, nullptr, 0);
  gemm_bt<0><<<dim3(18, 4, 8), 256, 0, stream>>>(h2t, Wbf, qk2, N, 512, C, sH,
                                                 0, sQK, bqk, nullptr, 0);
  gemm_bt<1><<<dim3(2, 18, 8), 256, 0, stream>>>(Wbf + 2 * 65536, h1t, vB, C,
                                                 N, C, 0, sH, sX, bv, nullptr,
                                                 0);

  flash_attn<<<576, 256, 0, stream>>>(qk1, qk2, vB, att1, att2);

  const size_t half = (size_t)8 * C * N;
  gemm_bt<5><<<dim3(2, 18, 8), 256, 0, stream>>>(Wbf + 3 * 65536, att1, out, C,
                                                 N, C, 0, sH, sX, bp, x1, sX);
  gemm_bt<5><<<dim3(2, 18, 8), 256, 0, stream>>>(Wbf + 3 * 65536, att2,
                                                 out + half, C, N, C, 0, sH,
                                                 sX, bp, x1, sX);
}

// Round 5
// 511.575 us; speedup vs baseline: 1.3288x; 1.3122x over previous
//
#include <hip/hip_runtime.h>
#include <stdint.h>

typedef unsigned short ushort_t;
typedef __attribute__((ext_vector_type(8))) short bf16x8;
typedef __attribute__((ext_vector_type(4))) float f32x4;
typedef __attribute__((ext_vector_type(16))) float f32x16;
typedef __attribute__((ext_vector_type(4))) unsigned short us4;

static __device__ __forceinline__ unsigned short f2bf(float f) {
  union { float f; uint32_t u; } v; v.f = f;
  uint32_t u = v.u;
  u += 0x7FFFu + ((u >> 16) & 1u);
  return (unsigned short)(u >> 16);
}

static __device__ __forceinline__ float wredsum(float v) {
#pragma unroll
  for (int o = 32; o > 0; o >>= 1) v += __shfl_down(v, o, 64);
  return v;
}

// ---------------------------------------------------------------------------
// Weight fp32 -> bf16 conversion (Wq|Wk|Wv|Wp into one slab)
// ---------------------------------------------------------------------------
__global__ __launch_bounds__(256) void cvt_w(
    const float* __restrict__ Wq, const float* __restrict__ Wk,
    const float* __restrict__ Wv, const float* __restrict__ Wp,
    ushort_t* __restrict__ dst) {
  int m = blockIdx.y;
  const float* src = (m == 0) ? Wq : (m == 1) ? Wk : (m == 2) ? Wv : Wp;
  int i = blockIdx.x * 256 + threadIdx.x;  // float4 index, 16384 per matrix
  float4 v = ((const float4*)src)[i];
  us4 o;
  o.x = f2bf(v.x); o.y = f2bf(v.y); o.z = f2bf(v.z); o.w = f2bf(v.w);
  *(us4*)&dst[(size_t)m * 65536 + (size_t)i * 4] = o;
}

__global__ __launch_bounds__(512) void pack_bqk(const float* __restrict__ bq,
                                                const float* __restrict__ bk,
                                                float* __restrict__ bqk) {
  int i = threadIdx.x;
  bqk[i] = (i < 256) ? bq[i] : bk[i - 256];
}

// ---------------------------------------------------------------------------
// GroupNorm stats: one block per (sel, b, g). mean + rstd over 8ch x 2304 px.
// ---------------------------------------------------------------------------
__global__ __launch_bounds__(256) void gn_stats(
    const float* __restrict__ x1, const float* __restrict__ x2,
    float* __restrict__ stats) {
  const int sel = blockIdx.x >> 8;
  const int bg = blockIdx.x & 255;  // b*32 + g
  const float* x = (sel ? x2 : x1) + (size_t)bg * 8 * 2304;
  float s = 0.f, ss = 0.f;
  for (int i = threadIdx.x; i < 4608; i += 256) {
    float4 v = ((const float4*)x)[i];
    s += v.x + v.y + v.z + v.w;
    ss += v.x * v.x + v.y * v.y + v.z * v.z + v.w * v.w;
  }
  s = wredsum(s);
  ss = wredsum(ss);
  __shared__ float ls[8];
  int wave = threadIdx.x >> 6, lane = threadIdx.x & 63;
  if (lane == 0) { ls[wave] = s; ls[4 + wave] = ss; }
  __syncthreads();
  if (threadIdx.x == 0) {
    float S = ls[0] + ls[1] + ls[2] + ls[3];
    float SS = ls[4] + ls[5] + ls[6] + ls[7];
    float mu = S * (1.f / 18432.f);
    float var = SS * (1.f / 18432.f) - mu * mu;
    stats[(sel * 256 + bg) * 2] = mu;
    stats[(sel * 256 + bg) * 2 + 1] = rsqrtf(var + 1e-6f);
  }
}

// ---------------------------------------------------------------------------
// GroupNorm apply + transpose: writes h_t[b][n][c] bf16. Block = (ntile,b,sel).
// ---------------------------------------------------------------------------
__global__ __launch_bounds__(256) void gn_apply(
    const float* __restrict__ x1, const float* __restrict__ x2,
    const float* __restrict__ gamma, const float* __restrict__ beta,
    const float* __restrict__ stats,
    ushort_t* __restrict__ h1t, ushort_t* __restrict__ h2t) {
  const int sel = blockIdx.z, b = blockIdx.y, nt = blockIdx.x;
  const int n0 = nt * 64;
  const float* x = (sel ? x2 : x1) + (size_t)b * 256 * 2304;
  ushort_t* ht = (sel ? h2t : h1t) + (size_t)b * 2304 * 256;
  const float* st = stats + (sel * 8 + b) * 64;  // 32 groups * 2
  __shared__ ushort_t lt[64 * 260];
#pragma unroll 4
  for (int it = 0; it < 64; ++it) {
    int flat = it * 256 + threadIdx.x;
    int c = flat >> 6, nn = flat & 63;
    float v = x[(size_t)c * 2304 + n0 + nn];
    int g = c >> 3;
    float mu = st[g * 2], rstd = st[g * 2 + 1];
    lt[nn * 260 + c] = f2bf((v - mu) * rstd * gamma[c] + beta[c]);
  }
  __syncthreads();
#pragma unroll 4
  for (int it = 0; it < 16; ++it) {
    int flat4 = it * 256 + threadIdx.x;
    int nn = flat4 >> 6, cq = flat4 & 63;
    us4 vv = *(const us4*)&lt[nn * 260 + cq * 4];
    *(us4*)&ht[(size_t)(n0 + nn) * 256 + cq * 4] = vv;
  }
}

// ---------------------------------------------------------------------------
// Generic both-K-contiguous MFMA GEMM.  C[m][n] = sum_k A[m][k]*B[n][k].
// 128x128 tile, BK=32, 256 threads (4 waves, 2x2 of 64x64), 16x16x32 bf16.
// MODE_OUT: 0 bf16 +bias[col] | 1 bf16 +bias[row]
//           5 fp32 = acc + bias[row] + res[row][col]
//           6 bf16 +bias[col]; col<256 -> row-major Q (Cv), col>=256 ->
//             fragment-major Kf (Cv2): ((n>>6)*32+(c'>>3))*64+(n&63))*8+(c'&7)
//           7 bf16 +bias[row]; fragment-major Vf:
//             ((col>>6)*8+((col>>3)&7))*256+row)*8+(col&7)
// ---------------------------------------------------------------------------
template <int MODE_OUT>
__global__ __launch_bounds__(256) void gemm_bt(
    const ushort_t* __restrict__ Av, const ushort_t* __restrict__ Bv,
    void* __restrict__ Cv, int M, int N, int K, long sA, long sB, long sC,
    const float* __restrict__ bias, const float* __restrict__ res, long sRes,
    void* __restrict__ Cv2) {
  __shared__ ushort_t lA[128 * 32];
  __shared__ ushort_t lB[128 * 32];
  const int tid = threadIdx.x;
  const int lane = tid & 63, wave = tid >> 6;
  const int wm = wave >> 1, wn = wave & 1;
  const int bz = blockIdx.z;
  const int bM = blockIdx.x * 128, bN = blockIdx.y * 128;

  const ushort_t* B = Bv + (size_t)bz * sB + (size_t)bN * K;
  const ushort_t* Ab = Av + (size_t)bz * sA + (size_t)bM * K;

  f32x4 acc[4][4];
#pragma unroll
  for (int m = 0; m < 4; ++m)
#pragma unroll
    for (int n = 0; n < 4; ++n) acc[m][n] = (f32x4){0.f, 0.f, 0.f, 0.f};

  const int nK = K >> 5;
  for (int kt = 0; kt < nK; ++kt) {
    __syncthreads();
#pragma unroll
    for (int i = 0; i < 2; ++i) {
      int c = i * 256 + tid;
      int row = c >> 2, cb = (c & 3) * 8;
      const ushort_t* src = B + (size_t)row * K + kt * 32 + cb;
      __builtin_amdgcn_global_load_lds(
          (const __attribute__((address_space(1))) uint32_t*)src,
          (__attribute__((address_space(3))) uint32_t*)((char*)lB + i * 4096 +
                                                        wave * 1024),
          16, 0, 0);
    }
#pragma unroll
    for (int i = 0; i < 2; ++i) {
      int c = i * 256 + tid;
      int row = c >> 2, cb = (c & 3) * 8;
      const ushort_t* src = Ab + (size_t)row * K + kt * 32 + cb;
      __builtin_amdgcn_global_load_lds(
          (const __attribute__((address_space(1))) uint32_t*)src,
          (__attribute__((address_space(3))) uint32_t*)((char*)lA + i * 4096 +
                                                        wave * 1024),
          16, 0, 0);
    }
    __syncthreads();

    bf16x8 af[4], bfr[4];
    const int ko = (lane >> 4) * 8;
    const int rb = lane & 15;
#pragma unroll
    for (int m = 0; m < 4; ++m)
      af[m] = *(const bf16x8*)&lA[(wm * 64 + m * 16 + rb) * 32 + ko];
#pragma unroll
    for (int n = 0; n < 4; ++n)
      bfr[n] = *(const bf16x8*)&lB[(wn * 64 + n * 16 + rb) * 32 + ko];
#pragma unroll
    for (int m = 0; m < 4; ++m)
#pragma unroll
      for (int n = 0; n < 4; ++n)
        acc[m][n] =
            __builtin_amdgcn_mfma_f32_16x16x32_bf16(af[m], bfr[n], acc[m][n],
                                                    0, 0, 0);
  }

  const int r0 = (lane >> 4) * 4;
  const int c0 = lane & 15;
#pragma unroll
  for (int m = 0; m < 4; ++m) {
#pragma unroll
    for (int n = 0; n < 4; ++n) {
#pragma unroll
      for (int j = 0; j < 4; ++j) {
        int row = bM + wm * 64 + m * 16 + r0 + j;
        int col = bN + wn * 64 + n * 16 + c0;
        float v = acc[m][n][j];
        size_t idx = (size_t)row * N + col;
        if (MODE_OUT == 0) {
          ((ushort_t*)Cv + (size_t)bz * sC)[idx] = f2bf(v + bias[col]);
        } else if (MODE_OUT == 1) {
          ((ushort_t*)Cv + (size_t)bz * sC)[idx] = f2bf(v + bias[row]);
        } else if (MODE_OUT == 5) {
          ((float*)Cv + (size_t)bz * sC)[idx] =
              v + bias[row] + (res + (size_t)bz * sRes)[idx];
        } else if (MODE_OUT == 6) {
          float vv = v + bias[col];
          if (col < 256) {
            ((ushort_t*)Cv + (size_t)bz * sC)[(size_t)row * 256 + col] =
                f2bf(vv);
          } else {
            int cp = col - 256;
            size_t kidx = (size_t)(row >> 6) * 16384 + (size_t)(cp >> 3) * 512 +
                          (size_t)(row & 63) * 8 + (cp & 7);
            ((ushort_t*)Cv2 + (size_t)bz * 589824)[kidx] = f2bf(vv);
          }
        } else if (MODE_OUT == 7) {
          size_t vidx = (size_t)(col >> 6) * 16384 +
                        (size_t)((col >> 3) & 7) * 2048 + (size_t)row * 8 +
                        (col & 7);
          ((ushort_t*)Cv + (size_t)bz * sC)[vidx] = f2bf(v + bias[row]);
        }
      }
    }
  }
}

// ---------------------------------------------------------------------------
// Fused dual attention, pair-split + software-pipelined:
//   waves 0/1: att1 = softmax(s*q1k1) @ v^T      (j/c halves)
//   waves 2/3: att2 = softmax(s*(q1k1+q2k2)) @ v^T
// K and V are FRAGMENT-MAJOR in global memory (written by projection GEMMs):
//   Kf[b][t][g=c>>3][j(64)][8]  -> a wave's fragment load = 512B contiguous
//   Vf[b][t][g=j>>3][c(256)][8] -> same
// so every inner-loop global load is perfectly coalesced (round-4 fix: the
// old row-major loads were 32-cache-line gathers, serializing the kernel).
// Q tile = 32 rows, Q in registers. P via swizzled LDS. Fixed-shift softmax
// exp(w-8). Phase 1: scores(t) + PV(t-1). Phase 2: cross pair builds P12.
// ---------------------------------------------------------------------------
__global__ __launch_bounds__(256, 2) void flash_attn(
    const ushort_t* __restrict__ q1t, const ushort_t* __restrict__ kf1,
    const ushort_t* __restrict__ q2t, const ushort_t* __restrict__ kf2,
    const ushort_t* __restrict__ vf, ushort_t* __restrict__ att1,
    ushort_t* __restrict__ att2) {
  const int bid = blockIdx.x;
  const int b = bid & 7;    // batch -> XCD affinity
  const int qb = bid >> 3;  // 0..71, 32 q-rows each
  const int tid = threadIdx.x;
  const int lane = tid & 63;
  const int w = tid >> 6;
  const int grp = w >> 1;  // 0 = self pair, 1 = cross pair
  const int wp = w & 1;    // j-half (scores) / c-half (PV)
  const int l31 = lane & 31;
  const int h = lane >> 5;

  const size_t sH = (size_t)2304 * 256;
  const ushort_t* qp0 = (grp ? q2t : q1t) + b * sH;
  const bf16x8* kb = (const bf16x8*)((grp ? kf2 : kf1) + b * sH);
  const bf16x8* vb = (const bf16x8*)(vf + b * sH);

  __shared__ ushort_t P1[2][32 * 64];  // self probs, double-buffered, swizzled
  __shared__ ushort_t P12[32 * 64];    // cross probs, swizzled
  __shared__ float S1[32 * 64];        // raw self scores, swizzled
  __shared__ float red[2][32];

  // ---- Q fragments (persist in registers; one-time gather) ----
  bf16x8 qf[16];
  {
    const ushort_t* qp = qp0 + (size_t)(qb * 32 + l31) * 256 + h * 8;
#pragma unroll
    for (int ck = 0; ck < 16; ++ck) qf[ck] = *(const bf16x8*)(qp + ck * 16);
  }

  f32x16 o[4];
#pragma unroll
  for (int cb = 0; cb < 4; ++cb)
#pragma unroll
    for (int r = 0; r < 16; ++r) o[cb][r] = 0.f;
  float lp = 0.f;
  const int iswz = (l31 & 7) << 4;

  auto do_pv = [&](int tt) {
    const ushort_t* pb = grp ? P12 : P1[tt & 1];
    const bf16x8* vt = vb + (size_t)tt * 2048;
#pragma unroll
    for (int jc = 0; jc < 4; ++jc) {
      bf16x8 pa = *(const bf16x8*)((const char*)pb +
                                   ((l31 * 128 + jc * 32 + h * 16) ^ iswz));
#pragma unroll
      for (int cb = 0; cb < 4; ++cb) {
        bf16x8 vfr = vt[(jc * 2 + h) * 256 + wp * 128 + cb * 32 + l31];
        o[cb] =
            __builtin_amdgcn_mfma_f32_32x32x16_bf16(pa, vfr, o[cb], 0, 0, 0);
      }
    }
  };

  f32x16 s2save;
  for (int t = 0; t < 36; ++t) {
    // ---------------- phase 1: scores(t) + PV(t-1) ----------------
    f32x16 s;
#pragma unroll
    for (int r = 0; r < 16; ++r) s[r] = 0.f;
    {
      const bf16x8* kt = kb + (size_t)t * 2048 + wp * 32 + l31;
#pragma unroll
      for (int ck = 0; ck < 16; ++ck) {
        bf16x8 kf = kt[(ck * 2 + h) * 64];
        s = __builtin_amdgcn_mfma_f32_32x32x16_bf16(kf, qf[ck], s, 0, 0, 0);
      }
    }
    if (t > 0) do_pv(t - 1);
    if (grp == 0) {
      float e[16];
#pragma unroll
      for (int r = 0; r < 16; ++r) {
        e[r] = __expf(s[r] * 0.0625f - 8.f);
        lp += e[r];
      }
      char* p1 = (char*)P1[t & 1];
      char* s1 = (char*)S1;
#pragma unroll
      for (int g = 0; g < 4; ++g) {
        uint32_t u0 = (uint32_t)f2bf(e[4 * g]) |
                      ((uint32_t)f2bf(e[4 * g + 1]) << 16);
        uint32_t u1 = (uint32_t)f2bf(e[4 * g + 2]) |
                      ((uint32_t)f2bf(e[4 * g + 3]) << 16);
        *(uint2*)(p1 + ((l31 * 128 + wp * 64 + g * 16 + h * 8) ^ iswz)) =
            make_uint2(u0, u1);
        float4 sv = make_float4(s[4 * g], s[4 * g + 1], s[4 * g + 2],
                                s[4 * g + 3]);
        *(float4*)(s1 + ((l31 * 256 + wp * 128 + g * 32 + h * 16) ^ iswz)) =
            sv;
      }
    } else {
      s2save = s;
    }
    __syncthreads();
    // ---------------- phase 2: cross pair builds P12(t) ----------------
    if (grp == 1) {
      const char* s1 = (const char*)S1;
      char* p12 = (char*)P12;
#pragma unroll
      for (int g = 0; g < 4; ++g) {
        float4 sv = *(const float4*)(s1 + ((l31 * 256 + wp * 128 + g * 32 +
                                            h * 16) ^ iswz));
        float e0 = __expf((sv.x + s2save[4 * g + 0]) * 0.0625f - 8.f);
        float e1 = __expf((sv.y + s2save[4 * g + 1]) * 0.0625f - 8.f);
        float e2 = __expf((sv.z + s2save[4 * g + 2]) * 0.0625f - 8.f);
        float e3 = __expf((sv.w + s2save[4 * g + 3]) * 0.0625f - 8.f);
        lp += e0 + e1 + e2 + e3;
        uint32_t u0 = (uint32_t)f2bf(e0) | ((uint32_t)f2bf(e1) << 16);
        uint32_t u1 = (uint32_t)f2bf(e2) | ((uint32_t)f2bf(e3) << 16);
        *(uint2*)(p12 + ((l31 * 128 + wp * 64 + g * 16 + h * 8) ^ iswz)) =
            make_uint2(u0, u1);
      }
    }
    __syncthreads();
  }
  do_pv(35);

  // ---- denominators: combine h halves, then the two waves of each pair ----
  lp += __shfl_xor(lp, 32, 64);
  __syncthreads();
  if (wp == 0 && lane < 32) red[grp][l31] = lp;
  __syncthreads();
  if (wp == 1 && lane < 32) red[grp][l31] += lp;
  __syncthreads();

  ushort_t* ap = (grp ? att2 : att1) + ((size_t)b * 2304 + qb * 32) * 256;
#pragma unroll
  for (int r = 0; r < 16; ++r) {
    int irow = (r & 3) + 8 * (r >> 2) + 4 * h;
    float rl = 1.f / red[grp][irow];
#pragma unroll
    for (int cb = 0; cb < 4; ++cb) {
      int col = wp * 128 + cb * 32 + l31;
      ap[(size_t)irow * 256 + col] = f2bf(o[cb][r] * rl);
    }
  }
}

// ---------------------------------------------------------------------------
extern "C" void kernel_launch(void* const* d_in, const int* in_sizes, int n_in,
                              void* d_out, int out_size, void* d_ws,
                              size_t ws_size, hipStream_t stream) {
  (void)in_sizes; (void)n_in; (void)out_size; (void)ws_size;
  const float* x1 = (const float*)d_in[0];
  const float* x2 = (const float*)d_in[1];
  const float* gamma = (const float*)d_in[2];
  const float* beta = (const float*)d_in[3];
  const float* Wq = (const float*)d_in[4];
  const float* bq = (const float*)d_in[5];
  const float* Wk = (const float*)d_in[6];
  const float* bk = (const float*)d_in[7];
  const float* Wv = (const float*)d_in[8];
  const float* bv = (const float*)d_in[9];
  const float* Wp = (const float*)d_in[10];
  const float* bp = (const float*)d_in[11];
  float* out = (float*)d_out;

  const int C = 256, N = 2304;
  const long sH = (long)N * C;
  const long sX = (long)C * N;
  const size_t HE = (size_t)8 * N * C;

  char* ws = (char*)d_ws;
  ushort_t* Wbf = (ushort_t*)ws;         // 4 * 65536 bf16
  float* stats = (float*)(ws + 524288);  // 1024 fp32
  float* bqk = (float*)(ws + 528384);    // 512 fp32
  ushort_t* h1t = (ushort_t*)(ws + 532480);
  ushort_t* h2t = h1t + HE;
  ushort_t* q1t = h2t + HE;   // [b][n][256]
  ushort_t* q2t = q1t + HE;
  ushort_t* kf1 = q2t + HE;   // fragment-major K
  ushort_t* kf2 = kf1 + HE;
  ushort_t* vfB = kf2 + HE;   // fragment-major V
  ushort_t* att1 = vfB + HE;  // [b][n][c]
  ushort_t* att2 = att1 + HE;

  cvt_w<<<dim3(64, 4), 256, 0, stream>>>(Wq, Wk, Wv, Wp, Wbf);
  pack_bqk<<<1, 512, 0, stream>>>(bq, bk, bqk);
  gn_stats<<<512, 256, 0, stream>>>(x1, x2, stats);
  gn_apply<<<dim3(36, 8, 2), 256, 0, stream>>>(x1, x2, gamma, beta, stats, h1t,
                                               h2t);

  // fused q|k projections (N=512) with split q/Kf epilogue; v -> Vf
  gemm_bt<6><<<dim3(18, 4, 8), 256, 0, stream>>>(h1t, Wbf, q1t, N, 512, C, sH,
                                                 0, sH, bqk, nullptr, 0, kf1);
  gemm_bt<6><<<dim3(18, 4, 8), 256, 0, stream>>>(h2t, Wbf, q2t, N, 512, C, sH,
                                                 0, sH, bqk, nullptr, 0, kf2);
  gemm_bt<7><<<dim3(2, 18, 8), 256, 0, stream>>>(Wbf + 2 * 65536, h1t, vfB, C,
                                                 N, C, 0, sH, sH, bv, nullptr,
                                                 0, nullptr);

  flash_attn<<<576, 256, 0, stream>>>(q1t, kf1, q2t, kf2, vfB, att1, att2);

  const size_t half = (size_t)8 * C * N;
  gemm_bt<5><<<dim3(2, 18, 8), 256, 0, stream>>>(Wbf + 3 * 65536, att1, out, C,
                                                 N, C, 0, sH, sX, bp, x1, sX,
                                                 nullptr);
  gemm_bt<5><<<dim3(2, 18, 8), 256, 0, stream>>>(Wbf + 3 * 65536, att2,
                                                 out + half, C, N, C, 0, sH,
                                                 sX, bp, x1, sX, nullptr);
}